// Round 19
// baseline (507.272 us; speedup 1.0000x reference)
//
#include <hip/hip_runtime.h>
#include <cmath>

#define T_SEQ 2048
#define C_DIM 1024
#define BM 128
#define BN 128
#define BK 32

typedef unsigned short u16;
typedef unsigned int u32;
typedef short bf16x8 __attribute__((ext_vector_type(8)));
typedef _Float16 f16x8 __attribute__((ext_vector_type(8)));
typedef float f32x4 __attribute__((ext_vector_type(4)));
typedef unsigned short u16x8 __attribute__((ext_vector_type(8)));

#define AS1 __attribute__((address_space(1)))
#define AS3 __attribute__((address_space(3)))

__device__ __forceinline__ u16 f2bf(float f) {
    u32 u = __builtin_bit_cast(u32, f);
    u32 r = u + 0x7fffu + ((u >> 16) & 1u);
    return (u16)(r >> 16);
}
__device__ __forceinline__ u16 f2h(float f) {
    return __builtin_bit_cast(u16, (_Float16)f);
}
__device__ __forceinline__ float h2f(u16 h) {
    return (float)__builtin_bit_cast(_Float16, h);
}
__device__ __forceinline__ void gl_lds16(const void* g, void* l) {
    __builtin_amdgcn_global_load_lds((const AS1 u32*)g, (AS3 u32*)l, 16, 0, 0);
}

// XCD-aware bijective block swizzle (T1): all our grids have nwg % 8 == 0.
__device__ __forceinline__ int xcd_swz(int lin, int nwg) {
    return (lin & 7) * (nwg >> 3) + (lin >> 3);
}

#define SBAR() do { __builtin_amdgcn_sched_barrier(0); \
                    __builtin_amdgcn_s_barrier(); \
                    __builtin_amdgcn_sched_barrier(0); } while (0)
#define VMC(n) do { asm volatile("s_waitcnt vmcnt(" #n ")" ::: "memory"); \
                    __builtin_amdgcn_sched_barrier(0); } while (0)
#define LGKM0() do { asm volatile("s_waitcnt lgkmcnt(0)" ::: "memory"); \
                     __builtin_amdgcn_sched_barrier(0); } while (0)

// ---------------------------------------------------------------------------
// 8-phase 256x256 fp16 GEMM, m201-anatomy phases (validated R13-R18).
// ---------------------------------------------------------------------------
__global__ __launch_bounds__(512, 2)
void gemm8(const u16* __restrict__ Ap, const u16* __restrict__ Bp,
           u16* __restrict__ Cout, int M, int N, int K)
{
    __shared__ u16 lds[2 * 32768];
    const int tid  = threadIdx.x;
    const int lane = tid & 63;
    const int wid  = tid >> 6;        // 0..7
    const int wrow = wid >> 2;        // 0..1
    const int wcol = wid & 3;         // 0..3
    const int gx = gridDim.x;
    const int lin = xcd_swz(blockIdx.x + gx * blockIdx.y, gx * gridDim.y);
    const int m0 = (lin / gx) * 256;
    const int n0 = (lin % gx) * 256;
    const int NT = K / 64;

    f32x4 acc[8][4] = {};

    auto stageu = [&](int t, int u) {
        const int isB = u & 1, kh = u >> 1;
        u16* ubase = &lds[(t & 1) * 32768 + isB * 16384 + kh * 8192];
        const u16* src = isB ? Bp + (size_t)n0 * K : Ap + (size_t)m0 * K;
        const int k0 = t * 64 + kh * 32;
        #pragma unroll
        for (int j = 0; j < 2; ++j) {
            const int c = wid + 8 * j;
            const int p = c * 64 + lane;
            const int row = p >> 2;
            const int sp  = (p & 3) ^ ((row >> 1) & 3);
            gl_lds16(src + (size_t)row * K + k0 + sp * 8, ubase + c * 512);
        }
    };

    auto lda = [&](int buf, int kh, int mq, f16x8 (&a)[4]) {
        const u16* base = &lds[buf * 32768 + kh * 8192];
        #pragma unroll
        for (int f = 0; f < 4; ++f) {
            const int row = wrow * 128 + mq * 64 + f * 16 + (lane & 15);
            const int sp  = (lane >> 4) ^ ((row >> 1) & 3);
            a[f] = *(const f16x8*)&base[row * 32 + sp * 8];
        }
    };
    auto ldb = [&](int buf, int kh, f16x8 (&b)[4]) {
        const u16* base = &lds[buf * 32768 + 16384 + kh * 8192];
        #pragma unroll
        for (int f = 0; f < 4; ++f) {
            const int row = wcol * 64 + f * 16 + (lane & 15);
            const int sp  = (lane >> 4) ^ ((row >> 1) & 3);
            b[f] = *(const f16x8*)&base[row * 32 + sp * 8];
        }
    };
    auto mm = [&](const f16x8 (&a)[4], const f16x8 (&b)[4], int mq) {
        __builtin_amdgcn_s_setprio(1);
        #pragma unroll
        for (int fm = 0; fm < 4; ++fm)
            #pragma unroll
            for (int fn = 0; fn < 4; ++fn)
                acc[mq * 4 + fm][fn] = __builtin_amdgcn_mfma_f32_16x16x32_f16(
                    a[fm], b[fn], acc[mq * 4 + fm][fn], 0, 0, 0);
        __builtin_amdgcn_s_setprio(0);
    };

    stageu(0, 0); stageu(0, 1); stageu(0, 2); stageu(0, 3);
    VMC(0);
    SBAR();

    f16x8 a[4], b[4];
    for (int t = 0; t < NT; ++t) {
        const int buf = t & 1;
        const bool more = (t + 1 < NT);
        lda(buf, 0, 0, a); ldb(buf, 0, b);
        if (more) stageu(t + 1, 0);
        SBAR(); LGKM0();
        mm(a, b, 0);
        SBAR();
        lda(buf, 0, 1, a);
        if (more) { stageu(t + 1, 1); VMC(4); } else { VMC(0); }
        SBAR(); LGKM0();
        mm(a, b, 1);
        SBAR();
        lda(buf, 1, 0, a); ldb(buf, 1, b);
        if (more) stageu(t + 1, 2);
        SBAR(); LGKM0();
        mm(a, b, 0);
        SBAR();
        lda(buf, 1, 1, a);
        if (more) { stageu(t + 1, 3); VMC(4); }
        SBAR(); LGKM0();
        mm(a, b, 1);
        SBAR();
    }

    const int crow0 = m0 + wrow * 128 + ((lane >> 4) << 2);
    const int ccol  = n0 + wcol * 64 + (lane & 15);
    #pragma unroll
    for (int mi = 0; mi < 8; ++mi)
        #pragma unroll
        for (int fn = 0; fn < 4; ++fn)
            #pragma unroll
            for (int r = 0; r < 4; ++r)
                Cout[(size_t)(crow0 + mi * 16 + r) * N + ccol + fn * 16] =
                    f2h(acc[mi][fn][r]);
}

// ---------------------------------------------------------------------------
// Conv-as-GEMM with F|G concatenated as B-rows + epilogue gate exchange:
//   H = bf16( tanh(conv(yb,Wf)) * sigmoid(conv(yb,Wg)) )
// Wcat[tap][colgroup][64 F-rows | 64 G-rows][k]. Block = 256M x 128 B-rows
// (= 64 real cols, both gates). 8 waves 4M x 2N: wcol 0 = F, wcol 1 = G for
// the SAME real (row,col) outputs; single acc[4][4] each; gemm8 phase anatomy
// (4+4 reads -> 16 MFMA, kh-pair 2-deep prefetch, VMC(3)/phase).
// Epilogue: G-waves publish acc via LDS (XOR-swizzled), F-waves combine.
// LDS 96 KB = 2 buf x (A 2x16KB + B 2x8KB).
// ---------------------------------------------------------------------------
__global__ __launch_bounds__(512, 1)
void convG(const u16* __restrict__ A, const u16* __restrict__ Wcat,
           u16* __restrict__ H, int M)
{
    __shared__ u16 lds[2 * 24576];
    const int tid  = threadIdx.x;
    const int lane = tid & 63;
    const int wid  = tid >> 6;
    const int wrow = wid >> 1;        // 0..3
    const int wcol = wid & 1;         // 0 = F, 1 = G
    const int gx = gridDim.x;         // 16
    const int lin = xcd_swz(blockIdx.x + gx * blockIdx.y, gx * gridDim.y);
    const int m0 = (lin / gx) * 256;
    const int nb = lin % gx;          // 64-real-col group
    const int NT = 32;                // 2 taps x 16 K-tiles (BK=64)

    f32x4 acc[4][4] = {};

    auto stageK = [&](int t, int kh) {
        const int tap = t >> 4;
        const int k0 = (t & 15) * 64 + kh * 32;
        {   // A half-tile: 256 rows x 32 k = 16 KB, 2 loads/thread
            u16* ubase = &lds[(t & 1) * 24576 + kh * 8192];
            const int sh = (tap == 0) ? 1 : 0;
            #pragma unroll
            for (int j = 0; j < 2; ++j) {
                const int c = tid + 512 * j;          // 0..1023
                const int row = c >> 2;               // 0..255
                const int sp  = (c & 3) ^ ((row >> 1) & 3);
                int grow = m0 + row - sh;
                if (grow < 0) grow = 0;
                gl_lds16(A + (size_t)grow * C_DIM + k0 + sp * 8, ubase + c * 8);
            }
        }
        {   // B half-tile: 128 rows x 32 k = 8 KB, 1 load/thread
            u16* ubase = &lds[(t & 1) * 24576 + 16384 + kh * 4096];
            const u16* src = Wcat + (size_t)tap * 2 * C_DIM * C_DIM
                           + (size_t)nb * 128 * C_DIM;
            const int row = tid >> 2;                 // 0..127
            const int sp  = (tid & 3) ^ ((row >> 1) & 3);
            gl_lds16(src + (size_t)row * C_DIM + k0 + sp * 8, ubase + tid * 8);
        }
    };

    auto lda4 = [&](int buf, int kh, bf16x8 (&a)[4]) {
        const u16* base = &lds[buf * 24576 + kh * 8192];
        #pragma unroll
        for (int f = 0; f < 4; ++f) {
            const int row = wrow * 64 + f * 16 + (lane & 15);
            const int sp  = (lane >> 4) ^ ((row >> 1) & 3);
            a[f] = *(const bf16x8*)&base[row * 32 + sp * 8];
        }
    };
    auto ldb4 = [&](int buf, int kh, bf16x8 (&b)[4]) {
        const u16* base = &lds[buf * 24576 + 16384 + kh * 4096];
        #pragma unroll
        for (int f = 0; f < 4; ++f) {
            const int row = wcol * 64 + f * 16 + (lane & 15);
            const int sp  = (lane >> 4) ^ ((row >> 1) & 3);
            b[f] = *(const bf16x8*)&base[row * 32 + sp * 8];
        }
    };
    auto mm = [&](const bf16x8 (&a)[4], const bf16x8 (&b)[4]) {
        __builtin_amdgcn_s_setprio(1);
        #pragma unroll
        for (int fm = 0; fm < 4; ++fm)
            #pragma unroll
            for (int fn = 0; fn < 4; ++fn)
                acc[fm][fn] = __builtin_amdgcn_mfma_f32_16x16x32_bf16(
                    a[fm], b[fn], acc[fm][fn], 0, 0, 0);
        __builtin_amdgcn_s_setprio(0);
    };

    const bool zrow  = (m0 % T_SEQ) == 0;              // block-uniform
    const bool zlane = (wrow == 0) && ((lane & 15) == 0);
    const bf16x8 zvec = {0,0,0,0,0,0,0,0};

    stageK(0, 0); stageK(0, 1);
    VMC(0);
    SBAR();

    bf16x8 a[4], b[4];
    for (int t = 0; t < NT; ++t) {
        const int buf = t & 1;
        const bool more = (t + 1 < NT);
        const bool z0 = zrow && (t < 16);              // tap-0 tiles
        // Ph1: kh0; stage kh0(t+1)
        lda4(buf, 0, a); ldb4(buf, 0, b);
        if (more) { stageK(t + 1, 0); VMC(3); } else { VMC(0); }
        SBAR(); LGKM0();
        if (z0 && zlane) a[0] = zvec;                  // causal zero
        mm(a, b);
        SBAR();
        // Ph2: kh1; stage kh1(t+1)
        lda4(buf, 1, a); ldb4(buf, 1, b);
        if (more) { stageK(t + 1, 1); VMC(3); } else { VMC(0); }
        SBAR(); LGKM0();
        if (z0 && zlane) a[0] = zvec;
        mm(a, b);
        SBAR();
    }

    // ---- epilogue: gate exchange (G-waves publish, F-waves combine) ----
    float* fl = (float*)lds;
    if (wcol == 1) {
        #pragma unroll
        for (int fm = 0; fm < 4; ++fm)
            #pragma unroll
            for (int fn = 0; fn < 4; ++fn) {
                const int s = (fm * 4 + fn) ^ (lane & 15);
                *(f32x4*)&fl[(size_t)wrow * 4096 + (size_t)lane * 64 + s * 4] = acc[fm][fn];
            }
    }
    LGKM0();
    SBAR();
    if (wcol == 0) {
        const int crow0 = m0 + wrow * 64 + ((lane >> 4) << 2);
        const int ccol  = nb * 64 + (lane & 15);
        #pragma unroll
        for (int fm = 0; fm < 4; ++fm)
            #pragma unroll
            for (int fn = 0; fn < 4; ++fn) {
                const int s = (fm * 4 + fn) ^ (lane & 15);
                const f32x4 g = *(const f32x4*)&fl[(size_t)wrow * 4096 + (size_t)lane * 64 + s * 4];
                #pragma unroll
                for (int r = 0; r < 4; ++r) {
                    const float fv = acc[fm][fn][r];
                    const float gv = g[r];
                    const float th = 1.0f - 2.0f / (expf(2.0f * fv) + 1.0f);
                    const float sg = 1.0f / (1.0f + expf(-gv));
                    H[(size_t)(crow0 + fm * 16 + r) * C_DIM + ccol + fn * 16] = f2bf(th * sg);
                }
            }
    }
}

// ---------------------------------------------------------------------------
// Dual GEMM + product epilogue (2-phase 128^2, known good):
//   out = (A1 @ B1^T) * (A2 @ B2^T)   elementwise, f32 out
// ---------------------------------------------------------------------------
__global__ __launch_bounds__(256)
void dual_gemm(const u16* __restrict__ A1, const u16* __restrict__ B1, int K1,
               const u16* __restrict__ A2, const u16* __restrict__ B2, int K2,
               float* __restrict__ out, int M, int N)
{
    __shared__ u16 lds[2 * 2 * 4096];
    const int tid  = threadIdx.x;
    const int lane = tid & 63;
    const int wid  = tid >> 6;
    const int wr = wid >> 1, wc = wid & 1;
    const int gx = gridDim.x;
    const int lin = xcd_swz(blockIdx.x + gx * blockIdx.y, gx * gridDim.y);
    const int m0 = (lin / gx) * BM;
    const int n0 = (lin % gx) * BN;

    f32x4 acc1[4][4] = {};
    f32x4 acc2[4][4] = {};

    auto stage = [&](const u16* Ap, const u16* Bp, int K, int it, int buf) {
        const int k0 = it * BK;
        u16* base = &lds[buf * 8192];
        #pragma unroll
        for (int i = 0; i < 2; ++i) {
            const int chunk = wid + 4 * i;
            const int rloc  = chunk * 16 + (lane >> 2);
            const int slot  = (lane & 3) ^ ((rloc >> 1) & 3);
            gl_lds16(Bp + (size_t)(n0 + rloc) * K + k0 + slot * 8,
                     base + 4096 + chunk * 512);
            gl_lds16(Ap + (size_t)(m0 + rloc) * K + k0 + slot * 8,
                     base + chunk * 512);
        }
    };

    auto compute = [&](int buf, f32x4 (&acc)[4][4]) {
        const u16* base = &lds[buf * 8192];
        bf16x8 a[4], b[4];
        #pragma unroll
        for (int f = 0; f < 4; ++f) {
            const int row = wr * 64 + f * 16 + (lane & 15);
            const int sp  = ((lane >> 4) & 3) ^ ((row >> 1) & 3);
            a[f] = *(const bf16x8*)&base[row * 32 + sp * 8];
            const int rowb = wc * 64 + f * 16 + (lane & 15);
            const int spb  = ((lane >> 4) & 3) ^ ((rowb >> 1) & 3);
            b[f] = *(const bf16x8*)&base[4096 + rowb * 32 + spb * 8];
        }
        #pragma unroll
        for (int fm = 0; fm < 4; ++fm)
            #pragma unroll
            for (int fn = 0; fn < 4; ++fn)
                acc[fm][fn] = __builtin_amdgcn_mfma_f32_16x16x32_bf16(a[fm], b[fn], acc[fm][fn], 0, 0, 0);
    };

    const int NT1 = K1 / BK, NT2 = K2 / BK;
    stage(A1, B1, K1, 0, 0);
    int cur = 0;
    for (int it = 0; it < NT1; ++it) {
        __syncthreads();
        if (it + 1 < NT1) stage(A1, B1, K1, it + 1, cur ^ 1);
        else              stage(A2, B2, K2, 0, cur ^ 1);   // cross-phase prefetch
        compute(cur, acc1);
        cur ^= 1;
    }
    for (int it = 0; it < NT2; ++it) {
        __syncthreads();
        if (it + 1 < NT2) stage(A2, B2, K2, it + 1, cur ^ 1);
        compute(cur, acc2);
        cur ^= 1;
    }

    const int crow0 = m0 + wr * 64 + ((lane >> 4) << 2);
    const int ccol  = n0 + wc * 64 + (lane & 15);
    #pragma unroll
    for (int fm = 0; fm < 4; ++fm)
        #pragma unroll
        for (int fn = 0; fn < 4; ++fn)
            #pragma unroll
            for (int r = 0; r < 4; ++r) {
                const size_t idx = (size_t)(crow0 + fm * 16 + r) * N + ccol + fn * 16;
                out[idx] = acc1[fm][fn][r] * acc2[fm][fn][r];
            }
}

// ---------------------------------------------------------------------------
// Segmented parallel scan, 3-pass streaming with 4x batched loads (R18 state).
// ---------------------------------------------------------------------------
#define SSEG 32
#define SCHB 32
#define SSL (T_SEQ / SSEG)   // 64

__global__ __launch_bounds__(1024, 1)
void scan_kernel(u16* __restrict__ kq, u16* __restrict__ xyb)
{
    __shared__ float  lmax[SSEG][SCHB];
    __shared__ float2 lprod[SSEG][SCHB];
    const int blk = blockIdx.x;
    const int b   = blk >> 5;
    const int c0  = (blk & 31) * SCHB;
    const int ch  = threadIdx.x & (SCHB - 1);
    const int seg = threadIdx.x >> 5;
    const int c   = c0 + ch;
    const int t0  = seg * SSL;
    const size_t baseh = (size_t)b * T_SEQ * 2048 + 2 * c + (size_t)t0 * 2048;
    const size_t base1 = (size_t)b * T_SEQ * C_DIM + c + (size_t)t0 * C_DIM;

    // P1: segment max, loads batched 4-ahead
    float m2 = 0.f;
    {
        size_t idx = baseh;
        for (int g = 0; g < SSL / 4; ++g) {
            const u32 v0 = *(const u32*)&kq[idx];
            const u32 v1 = *(const u32*)&kq[idx + 2048];
            const u32 v2 = *(const u32*)&kq[idx + 4096];
            const u32 v3 = *(const u32*)&kq[idx + 6144];
            float re, im;
            re = h2f((u16)(v0 & 0xffffu)); im = h2f((u16)(v0 >> 16)); m2 = fmaxf(m2, re*re + im*im);
            re = h2f((u16)(v1 & 0xffffu)); im = h2f((u16)(v1 >> 16)); m2 = fmaxf(m2, re*re + im*im);
            re = h2f((u16)(v2 & 0xffffu)); im = h2f((u16)(v2 >> 16)); m2 = fmaxf(m2, re*re + im*im);
            re = h2f((u16)(v3 & 0xffffu)); im = h2f((u16)(v3 >> 16)); m2 = fmaxf(m2, re*re + im*im);
            idx += 4 * 2048;
        }
    }
    lmax[seg][ch] = sqrtf(m2);
    __syncthreads();
    #pragma unroll
    for (int s = 1; s < SSEG; s <<= 1) {
        const float v = lmax[seg][ch];
        const float u = (seg >= s) ? lmax[seg - s][ch] : 0.f;
        __syncthreads();
        lmax[seg][ch] = fmaxf(v, u);
        __syncthreads();
    }
    const float premax = (seg > 0) ? lmax[seg - 1][ch] : 0.f;

    // P2: seeded products + yb RMW, loads batched 4-ahead
    float pr = 1.f, pi = 0.f;
    float m = premax;
    {
        size_t idx = baseh, idx1 = base1;
        for (int g = 0; g < SSL / 4; ++g) {
            const u32 v0 = *(const u32*)&kq[idx];
            const u32 v1 = *(const u32*)&kq[idx + 2048];
            const u32 v2 = *(const u32*)&kq[idx + 4096];
            const u32 v3 = *(const u32*)&kq[idx + 6144];
            const u16 x0 = xyb[idx1];
            const u16 x1 = xyb[idx1 + C_DIM];
            const u16 x2 = xyb[idx1 + 2 * C_DIM];
            const u16 x3 = xyb[idx1 + 3 * C_DIM];
            u32 vv[4] = {v0, v1, v2, v3};
            u16 xx[4] = {x0, x1, x2, x3};
            #pragma unroll
            for (int q = 0; q < 4; ++q) {
                const float re = h2f((u16)(vv[q] & 0xffffu));
                const float im = h2f((u16)(vv[q] >> 16));
                m = fmaxf(m, sqrtf(re * re + im * im));
                const float inv = 1.f / m;
                const float r0 = re * inv, r1 = im * inv;
                const float nr = pr * r0 - pi * r1;
                const float ni = pr * r1 + pi * r0;
                pr = nr; pi = ni;
                xyb[idx1 + (size_t)q * C_DIM] = f2bf(h2f(xx[q]) * m);
            }
            idx += 4 * 2048; idx1 += 4 * C_DIM;
        }
    }
    lprod[seg][ch] = make_float2(pr, pi);
    __syncthreads();
    #pragma unroll
    for (int s = 1; s < SSEG; s <<= 1) {
        const float2 v = lprod[seg][ch];
        const float2 u = (seg >= s) ? lprod[seg - s][ch] : make_float2(1.f, 0.f);
        __syncthreads();
        lprod[seg][ch] = make_float2(u.x * v.x - u.y * v.y,
                                     u.x * v.y + u.y * v.x);
        __syncthreads();
    }
    float ppr = 1.f, ppi = 0.f;
    if (seg > 0) { const float2 pp = lprod[seg - 1][ch]; ppr = pp.x; ppi = pp.y; }

    // P3: recompute, scale by prefix, write kv (loads batched 4-ahead)
    pr = 1.f; pi = 0.f;
    m = premax;
    {
        size_t idx = baseh;
        for (int g = 0; g < SSL / 4; ++g) {
            const u32 v0 = *(const u32*)&kq[idx];
            const u32 v1 = *(const u32*)&kq[idx + 2048];
            const u32 v2 = *(const u32*)&kq[idx + 4096];
            const u32 v3 = *(const u32*)&kq[idx + 6144];
            u32 vv[4] = {v0, v1, v2, v3};
            u32 ww[4];
            #pragma unroll
            for (int q = 0; q < 4; ++q) {
                const float re = h2f((u16)(vv[q] & 0xffffu));
                const float im = h2f((u16)(vv[q] >> 16));
                m = fmaxf(m, sqrtf(re * re + im * im));
                const float inv = 1.f / m;
                const float r0 = re * inv, r1 = im * inv;
                const float nr = pr * r0 - pi * r1;
                const float ni = pr * r1 + pi * r0;
                pr = nr; pi = ni;
                const float fr = ppr * nr - ppi * ni;
                const float fi = ppr * ni + ppi * nr;
                ww[q] = ((u32)f2bf(fi) << 16) | (u32)f2bf(fr);
            }
            *(u32*)&kq[idx]        = ww[0];
            *(u32*)&kq[idx + 2048] = ww[1];
            *(u32*)&kq[idx + 4096] = ww[2];
            *(u32*)&kq[idx + 6144] = ww[3];
            idx += 4 * 2048;
        }
    }
}

// ---------------------------------------------------------------------------
// Prep kernels
// ---------------------------------------------------------------------------
__global__ void cvt_weights(const float* __restrict__ Wk, const float* __restrict__ Wa,
                            const float* __restrict__ Wo, u16* __restrict__ Wkh,
                            u16* __restrict__ Wab, u16* __restrict__ Wob)
{
    const int n1 = 2048 * 1024, n2 = 2 * 2048 * 1024, n3 = n2 + 1024 * 1024;
    const int i = (blockIdx.x * blockDim.x + threadIdx.x) * 4;
    if (i < n1) {
        const float4 v = *(const float4*)&Wk[i];
        ushort4 o; o.x = f2h(v.x); o.y = f2h(v.y); o.z = f2h(v.z); o.w = f2h(v.w);
        *(ushort4*)&Wkh[i] = o;
    } else if (i < n2) {
        const int j = i - n1;
        const float4 v = *(const float4*)&Wa[j];
        ushort4 o; o.x = f2bf(v.x); o.y = f2bf(v.y); o.z = f2bf(v.z); o.w = f2bf(v.w);
        *(ushort4*)&Wab[j] = o;
    } else if (i < n3) {
        const int j = i - n2;
        const float4 v = *(const float4*)&Wo[j];
        ushort4 o; o.x = f2bf(v.x); o.y = f2bf(v.y); o.z = f2bf(v.z); o.w = f2bf(v.w);
        *(ushort4*)&Wob[j] = o;
    }
}

__global__ void cvt_f16(const float* __restrict__ src, u16* __restrict__ dst, int n)
{
    const int i = (blockIdx.x * blockDim.x + threadIdx.x) * 4;
    if (i >= n) return;
    const float4 v = *(const float4*)&src[i];
    ushort4 o;
    o.x = f2h(v.x); o.y = f2h(v.y); o.z = f2h(v.z); o.w = f2h(v.w);
    *(ushort4*)&dst[i] = o;
}

// Wf/Wg [2,K,N] (tap,k,n) -> Wcat[tap][n>>6][(n&63) + 64*isG][k]  bf16
__global__ __launch_bounds__(256)
void wtrans(const float* __restrict__ Wf, const float* __restrict__ Wg,
            u16* __restrict__ dst)
{
    __shared__ float tile[64][65];
    const int z = blockIdx.z;                     // 0,1 F-taps; 2,3 G-taps
    const float* src = ((z < 2) ? Wf : Wg) + (size_t)(z & 1) * C_DIM * C_DIM;
    u16* d = dst + (size_t)(z & 1) * 2 * C_DIM * C_DIM;
    const int isG = (z >= 2) ? 1 : 0;
    const int k0 = blockIdx.x * 64;
    const int n0 = blockIdx.y * 64;
    const int tx = threadIdx.x & 63, ty = threadIdx.x >> 6;
    #pragma unroll
    for (int i = 0; i < 16; ++i) {
        const int r = ty + i * 4;
        tile[r][tx] = src[(size_t)(k0 + r) * C_DIM + n0 + tx];
    }
    __syncthreads();
    #pragma unroll
    for (int i = 0; i < 16; ++i) {
        const int r = ty + i * 4;   // real col offset within group
        d[(size_t)(n0 >> 6) * 128 * C_DIM + (size_t)(r + isG * 64) * C_DIM + k0 + tx]
            = f2bf(tile[tx][r]);
    }
}

// ---------------------------------------------------------------------------
// ws layout (bytes):
//   0         : kq  u16 [16384,2048]  67.1MB  (kh fp16 -> kv bf16 in-place)
//   67108864  : yb  u16 [16384,1024]  33.6MB  (xh fp16 -> yb bf16 in-place)
//   100663296 : hb  u16 [16384,1024]  33.6MB
//   134217728 : Wkh(f16) 4.2 | Wab 4.2 | Wcat 8.4 | Wob 2.1   (~153MB total)
// ---------------------------------------------------------------------------
extern "C" void kernel_launch(void* const* d_in, const int* in_sizes, int n_in,
                              void* d_out, int out_size, void* d_ws, size_t ws_size,
                              hipStream_t stream)
{
    const float* x  = (const float*)d_in[0];
    const float* Wk = (const float*)d_in[1];
    const float* Wa = (const float*)d_in[2];
    const float* Wf = (const float*)d_in[3];
    const float* Wg = (const float*)d_in[4];
    const float* Wo = (const float*)d_in[5];
    float* out = (float*)d_out;

    const int M = 8 * T_SEQ;
    u16* kq   = (u16*)d_ws;
    u16* yb   = (u16*)((char*)d_ws + 67108864ull);   // xh first, then yb
    u16* hb   = (u16*)((char*)d_ws + 100663296ull);
    u16* Wkh  = (u16*)((char*)d_ws + 134217728ull);
    u16* Wab  = Wkh + 2048 * 1024;
    u16* Wcat = Wab + 2048 * 1024;
    u16* Wob  = Wcat + 2ull * 2048 * 1024;

    cvt_weights<<<(5 * 1024 * 1024 / 4 + 255) / 256, 256, 0, stream>>>(
        Wk, Wa, Wo, Wkh, Wab, Wob);
    wtrans  <<<dim3(16, 16, 4), 256, 0, stream>>>(Wf, Wg, Wcat);
    cvt_f16 <<<(M * 1024 / 4) / 256, 256, 0, stream>>>(x, yb, M * 1024);  // xh

    // 1) kq = fp16( x @ Wk^T )  (8-phase 256^2 fp16 MFMA)
    gemm8<<<dim3(2048 / 256, M / 256), 512, 0, stream>>>(
        yb, Wkh, kq, M, 2048, 1024);

    // 2) streaming scan (4x batched loads): kv bf16 in-place; yb in-place
    scan_kernel<<<256, 1024, 0, stream>>>(kq, yb);

    // 3) hb = bf16(tanh(conv(yb,Wf)) * sigmoid(conv(yb,Wg)))  (conv-as-GEMM)
    convG<<<dim3(16, M / 256), 512, 0, stream>>>(yb, Wcat, hb, M);

    // 4) out = (kv @ Wa^T) * (hb @ Wo^T)   (dual GEMM, product epilogue)
    dual_gemm<<<dim3(1024 / BN, M / BM), 256, 0, stream>>>(
        kq, Wab, 2048, hb, Wob, 1024, out, M, 1024);
}

// Round 20
// 448.153 us; speedup vs baseline: 1.1319x; 1.1319x over previous
//
#include <hip/hip_runtime.h>
#include <cmath>

#define T_SEQ 2048
#define C_DIM 1024
#define BM 128
#define BN 128
#define BK 32

typedef unsigned short u16;
typedef unsigned int u32;
typedef short bf16x8 __attribute__((ext_vector_type(8)));
typedef _Float16 f16x8 __attribute__((ext_vector_type(8)));
typedef float f32x4 __attribute__((ext_vector_type(4)));
typedef unsigned short u16x8 __attribute__((ext_vector_type(8)));

#define AS1 __attribute__((address_space(1)))
#define AS3 __attribute__((address_space(3)))

__device__ __forceinline__ u16 f2bf(float f) {
    u32 u = __builtin_bit_cast(u32, f);
    u32 r = u + 0x7fffu + ((u >> 16) & 1u);
    return (u16)(r >> 16);
}
__device__ __forceinline__ u16 f2h(float f) {
    return __builtin_bit_cast(u16, (_Float16)f);
}
__device__ __forceinline__ float h2f(u16 h) {
    return (float)__builtin_bit_cast(_Float16, h);
}
__device__ __forceinline__ void gl_lds16(const void* g, void* l) {
    __builtin_amdgcn_global_load_lds((const AS1 u32*)g, (AS3 u32*)l, 16, 0, 0);
}

// XCD-aware bijective block swizzle (T1): all our grids have nwg % 8 == 0.
__device__ __forceinline__ int xcd_swz(int lin, int nwg) {
    return (lin & 7) * (nwg >> 3) + (lin >> 3);
}

#define SBAR() do { __builtin_amdgcn_sched_barrier(0); \
                    __builtin_amdgcn_s_barrier(); \
                    __builtin_amdgcn_sched_barrier(0); } while (0)
#define VMC(n) do { asm volatile("s_waitcnt vmcnt(" #n ")" ::: "memory"); \
                    __builtin_amdgcn_sched_barrier(0); } while (0)
#define LGKM0() do { asm volatile("s_waitcnt lgkmcnt(0)" ::: "memory"); \
                     __builtin_amdgcn_sched_barrier(0); } while (0)

// ---------------------------------------------------------------------------
// 8-phase 256x256 fp16 GEMM, m201-anatomy phases (validated R13-R18).
// ---------------------------------------------------------------------------
__global__ __launch_bounds__(512, 2)
void gemm8(const u16* __restrict__ Ap, const u16* __restrict__ Bp,
           u16* __restrict__ Cout, int M, int N, int K)
{
    __shared__ u16 lds[2 * 32768];
    const int tid  = threadIdx.x;
    const int lane = tid & 63;
    const int wid  = tid >> 6;        // 0..7
    const int wrow = wid >> 2;        // 0..1
    const int wcol = wid & 3;         // 0..3
    const int gx = gridDim.x;
    const int lin = xcd_swz(blockIdx.x + gx * blockIdx.y, gx * gridDim.y);
    const int m0 = (lin / gx) * 256;
    const int n0 = (lin % gx) * 256;
    const int NT = K / 64;

    f32x4 acc[8][4] = {};

    auto stageu = [&](int t, int u) {
        const int isB = u & 1, kh = u >> 1;
        u16* ubase = &lds[(t & 1) * 32768 + isB * 16384 + kh * 8192];
        const u16* src = isB ? Bp + (size_t)n0 * K : Ap + (size_t)m0 * K;
        const int k0 = t * 64 + kh * 32;
        #pragma unroll
        for (int j = 0; j < 2; ++j) {
            const int c = wid + 8 * j;
            const int p = c * 64 + lane;
            const int row = p >> 2;
            const int sp  = (p & 3) ^ ((row >> 1) & 3);
            gl_lds16(src + (size_t)row * K + k0 + sp * 8, ubase + c * 512);
        }
    };

    auto lda = [&](int buf, int kh, int mq, f16x8 (&a)[4]) {
        const u16* base = &lds[buf * 32768 + kh * 8192];
        #pragma unroll
        for (int f = 0; f < 4; ++f) {
            const int row = wrow * 128 + mq * 64 + f * 16 + (lane & 15);
            const int sp  = (lane >> 4) ^ ((row >> 1) & 3);
            a[f] = *(const f16x8*)&base[row * 32 + sp * 8];
        }
    };
    auto ldb = [&](int buf, int kh, f16x8 (&b)[4]) {
        const u16* base = &lds[buf * 32768 + 16384 + kh * 8192];
        #pragma unroll
        for (int f = 0; f < 4; ++f) {
            const int row = wcol * 64 + f * 16 + (lane & 15);
            const int sp  = (lane >> 4) ^ ((row >> 1) & 3);
            b[f] = *(const f16x8*)&base[row * 32 + sp * 8];
        }
    };
    auto mm = [&](const f16x8 (&a)[4], const f16x8 (&b)[4], int mq) {
        __builtin_amdgcn_s_setprio(1);
        #pragma unroll
        for (int fm = 0; fm < 4; ++fm)
            #pragma unroll
            for (int fn = 0; fn < 4; ++fn)
                acc[mq * 4 + fm][fn] = __builtin_amdgcn_mfma_f32_16x16x32_f16(
                    a[fm], b[fn], acc[mq * 4 + fm][fn], 0, 0, 0);
        __builtin_amdgcn_s_setprio(0);
    };

    stageu(0, 0); stageu(0, 1); stageu(0, 2); stageu(0, 3);
    VMC(0);
    SBAR();

    f16x8 a[4], b[4];
    for (int t = 0; t < NT; ++t) {
        const int buf = t & 1;
        const bool more = (t + 1 < NT);
        lda(buf, 0, 0, a); ldb(buf, 0, b);
        if (more) stageu(t + 1, 0);
        SBAR(); LGKM0();
        mm(a, b, 0);
        SBAR();
        lda(buf, 0, 1, a);
        if (more) { stageu(t + 1, 1); VMC(4); } else { VMC(0); }
        SBAR(); LGKM0();
        mm(a, b, 1);
        SBAR();
        lda(buf, 1, 0, a); ldb(buf, 1, b);
        if (more) stageu(t + 1, 2);
        SBAR(); LGKM0();
        mm(a, b, 0);
        SBAR();
        lda(buf, 1, 1, a);
        if (more) { stageu(t + 1, 3); VMC(4); }
        SBAR(); LGKM0();
        mm(a, b, 1);
        SBAR();
    }

    const int crow0 = m0 + wrow * 128 + ((lane >> 4) << 2);
    const int ccol  = n0 + wcol * 64 + (lane & 15);
    #pragma unroll
    for (int mi = 0; mi < 8; ++mi)
        #pragma unroll
        for (int fn = 0; fn < 4; ++fn)
            #pragma unroll
            for (int r = 0; r < 4; ++r)
                Cout[(size_t)(crow0 + mi * 16 + r) * N + ccol + fn * 16] =
                    f2h(acc[mi][fn][r]);
}

// ---------------------------------------------------------------------------
// Merged-phase fused causal-conv + gate (best conv variant, R17/R18):
//   H = bf16( tanh(conv(yb,Wf)) * sigmoid(conv(yb,Wg)) )
// Tile 256M x 128N, 8 waves 4M x 2N, per-wave 64x64 per gate.
// Per phase (one kh-half): {lda4 + ldb4(F) + ldb4(G) | stage A+B half of t+1 |
//   VMC(4)} -> SBAR -> lgkm -> 32 MFMA (F then G, A reused) -> SBAR.
// ---------------------------------------------------------------------------
__global__ __launch_bounds__(512, 2)
void conv8(const u16* __restrict__ A, const u16* __restrict__ Wfgt,
           u16* __restrict__ H, int M)
{
    __shared__ u16 lds[2 * 32768];
    const int tid  = threadIdx.x;
    const int lane = tid & 63;
    const int wid  = tid >> 6;
    const int wrow = wid >> 1;        // 0..3
    const int wcol = wid & 1;         // 0..1
    const int gx = gridDim.x;         // 8
    const int lin = xcd_swz(blockIdx.x + gx * blockIdx.y, gx * gridDim.y);
    const int m0 = (lin / gx) * 256;
    const int n0 = (lin % gx) * 128;
    const int NT = 32;                // 2 taps x 16 K-tiles

    f32x4 accF[4][4] = {};
    f32x4 accG[4][4] = {};

    auto stageA = [&](int t, int kh) {
        u16* ubase = &lds[(t & 1) * 32768 + kh * 8192];
        const int tap = t >> 4;
        const int k0 = (t & 15) * 64 + kh * 32;
        const int sh = (tap == 0) ? 1 : 0;
        #pragma unroll
        for (int j = 0; j < 2; ++j) {
            const int c = wid + 8 * j;
            const int p = c * 64 + lane;
            const int row = p >> 2;
            const int sp  = (p & 3) ^ ((row >> 1) & 3);
            int grow = m0 + row - sh;
            if (grow < 0) grow = 0;
            gl_lds16(A + (size_t)grow * C_DIM + k0 + sp * 8, ubase + c * 512);
        }
    };
    auto stageB = [&](int t, int kh) {
        u16* ubase = &lds[(t & 1) * 32768 + 16384 + kh * 8192];
        const int tap = t >> 4;
        const int k0 = (t & 15) * 64 + kh * 32;
        const u16* BF = Wfgt + (size_t)tap * 2 * C_DIM * C_DIM;
        const u16* BG = BF + (size_t)C_DIM * C_DIM;
        #pragma unroll
        for (int j = 0; j < 2; ++j) {
            const int c = wid + 8 * j;
            const int isG = c >> 3;
            const int p = (c & 7) * 64 + lane;
            const int row = p >> 2;
            const int sp  = (p & 3) ^ ((row >> 1) & 3);
            const u16* src = (isG ? BG : BF) + (size_t)(n0 + row) * C_DIM + k0 + sp * 8;
            gl_lds16(src, ubase + isG * 4096 + (c & 7) * 512);
        }
    };

    auto lda4 = [&](int buf, int kh, bf16x8 (&a)[4]) {
        const u16* base = &lds[buf * 32768 + kh * 8192];
        #pragma unroll
        for (int f = 0; f < 4; ++f) {
            const int row = wrow * 64 + f * 16 + (lane & 15);
            const int sp  = (lane >> 4) ^ ((row >> 1) & 3);
            a[f] = *(const bf16x8*)&base[row * 32 + sp * 8];
        }
    };
    auto ldb4 = [&](int buf, int kh, int isG, bf16x8 (&b)[4]) {
        const u16* base = &lds[buf * 32768 + 16384 + kh * 8192 + isG * 4096];
        #pragma unroll
        for (int f = 0; f < 4; ++f) {
            const int row = wcol * 64 + f * 16 + (lane & 15);
            const int sp  = (lane >> 4) ^ ((row >> 1) & 3);
            b[f] = *(const bf16x8*)&base[row * 32 + sp * 8];
        }
    };
    auto mm4 = [&](const bf16x8 (&a)[4], const bf16x8 (&b)[4], f32x4 (&acc)[4][4]) {
        #pragma unroll
        for (int fm = 0; fm < 4; ++fm)
            #pragma unroll
            for (int fn = 0; fn < 4; ++fn)
                acc[fm][fn] = __builtin_amdgcn_mfma_f32_16x16x32_bf16(
                    a[fm], b[fn], acc[fm][fn], 0, 0, 0);
    };

    const bool zrow = (m0 % T_SEQ) == 0;        // block-uniform
    const bool zlane = (wrow == 0) && ((lane & 15) == 0);
    const bf16x8 zvec = {0,0,0,0,0,0,0,0};

    stageA(0, 0); stageB(0, 0); stageA(0, 1); stageB(0, 1);
    VMC(0);
    SBAR();

    bf16x8 a[4], bF[4], bG[4];
    for (int t = 0; t < NT; ++t) {
        const int buf = t & 1;
        const bool more = (t + 1 < NT);
        const bool z0 = zrow && (t < 16);       // tap-0 pass only
        // Q1: kh0 (F+G); stage A+B kh0(t+1)
        lda4(buf, 0, a); ldb4(buf, 0, 0, bF); ldb4(buf, 0, 1, bG);
        if (more) { stageA(t + 1, 0); stageB(t + 1, 0); VMC(4); } else { VMC(0); }
        SBAR(); LGKM0();
        if (z0 && zlane) a[0] = zvec;           // causal zero, after data landed
        __builtin_amdgcn_s_setprio(1);
        mm4(a, bF, accF); mm4(a, bG, accG);
        __builtin_amdgcn_s_setprio(0);
        SBAR();
        // Q2: kh1 (F+G); stage A+B kh1(t+1)
        lda4(buf, 1, a); ldb4(buf, 1, 0, bF); ldb4(buf, 1, 1, bG);
        if (more) { stageA(t + 1, 1); stageB(t + 1, 1); VMC(4); } else { VMC(0); }
        SBAR(); LGKM0();
        if (z0 && zlane) a[0] = zvec;
        __builtin_amdgcn_s_setprio(1);
        mm4(a, bF, accF); mm4(a, bG, accG);
        __builtin_amdgcn_s_setprio(0);
        SBAR();
    }

    const int crow0 = m0 + wrow * 64 + ((lane >> 4) << 2);
    const int ccol  = n0 + wcol * 64 + (lane & 15);
    #pragma unroll
    for (int fm = 0; fm < 4; ++fm)
        #pragma unroll
        for (int fn = 0; fn < 4; ++fn)
            #pragma unroll
            for (int r = 0; r < 4; ++r) {
                const float fv = accF[fm][fn][r];
                const float gv = accG[fm][fn][r];
                const float th = 1.0f - 2.0f / (expf(2.0f * fv) + 1.0f);
                const float sg = 1.0f / (1.0f + expf(-gv));
                H[(size_t)(crow0 + fm * 16 + r) * C_DIM + ccol + fn * 16] = f2bf(th * sg);
            }
}

// ---------------------------------------------------------------------------
// Dual GEMM + product epilogue (2-phase 128^2, known good):
//   out = (A1 @ B1^T) * (A2 @ B2^T)   elementwise, f32 out
// ---------------------------------------------------------------------------
__global__ __launch_bounds__(256)
void dual_gemm(const u16* __restrict__ A1, const u16* __restrict__ B1, int K1,
               const u16* __restrict__ A2, const u16* __restrict__ B2, int K2,
               float* __restrict__ out, int M, int N)
{
    __shared__ u16 lds[2 * 2 * 4096];
    const int tid  = threadIdx.x;
    const int lane = tid & 63;
    const int wid  = tid >> 6;
    const int wr = wid >> 1, wc = wid & 1;
    const int gx = gridDim.x;
    const int lin = xcd_swz(blockIdx.x + gx * blockIdx.y, gx * gridDim.y);
    const int m0 = (lin / gx) * BM;
    const int n0 = (lin % gx) * BN;

    f32x4 acc1[4][4] = {};
    f32x4 acc2[4][4] = {};

    auto stage = [&](const u16* Ap, const u16* Bp, int K, int it, int buf) {
        const int k0 = it * BK;
        u16* base = &lds[buf * 8192];
        #pragma unroll
        for (int i = 0; i < 2; ++i) {
            const int chunk = wid + 4 * i;
            const int rloc  = chunk * 16 + (lane >> 2);
            const int slot  = (lane & 3) ^ ((rloc >> 1) & 3);
            gl_lds16(Bp + (size_t)(n0 + rloc) * K + k0 + slot * 8,
                     base + 4096 + chunk * 512);
            gl_lds16(Ap + (size_t)(m0 + rloc) * K + k0 + slot * 8,
                     base + chunk * 512);
        }
    };

    auto compute = [&](int buf, f32x4 (&acc)[4][4]) {
        const u16* base = &lds[buf * 8192];
        bf16x8 a[4], b[4];
        #pragma unroll
        for (int f = 0; f < 4; ++f) {
            const int row = wr * 64 + f * 16 + (lane & 15);
            const int sp  = ((lane >> 4) & 3) ^ ((row >> 1) & 3);
            a[f] = *(const bf16x8*)&base[row * 32 + sp * 8];
            const int rowb = wc * 64 + f * 16 + (lane & 15);
            const int spb  = ((lane >> 4) & 3) ^ ((rowb >> 1) & 3);
            b[f] = *(const bf16x8*)&base[4096 + rowb * 32 + spb * 8];
        }
        #pragma unroll
        for (int fm = 0; fm < 4; ++fm)
            #pragma unroll
            for (int fn = 0; fn < 4; ++fn)
                acc[fm][fn] = __builtin_amdgcn_mfma_f32_16x16x32_bf16(a[fm], b[fn], acc[fm][fn], 0, 0, 0);
    };

    const int NT1 = K1 / BK, NT2 = K2 / BK;
    stage(A1, B1, K1, 0, 0);
    int cur = 0;
    for (int it = 0; it < NT1; ++it) {
        __syncthreads();
        if (it + 1 < NT1) stage(A1, B1, K1, it + 1, cur ^ 1);
        else              stage(A2, B2, K2, 0, cur ^ 1);   // cross-phase prefetch
        compute(cur, acc1);
        cur ^= 1;
    }
    for (int it = 0; it < NT2; ++it) {
        __syncthreads();
        if (it + 1 < NT2) stage(A2, B2, K2, it + 1, cur ^ 1);
        compute(cur, acc2);
        cur ^= 1;
    }

    const int crow0 = m0 + wr * 64 + ((lane >> 4) << 2);
    const int ccol  = n0 + wc * 64 + (lane & 15);
    #pragma unroll
    for (int fm = 0; fm < 4; ++fm)
        #pragma unroll
        for (int fn = 0; fn < 4; ++fn)
            #pragma unroll
            for (int r = 0; r < 4; ++r) {
                const size_t idx = (size_t)(crow0 + fm * 16 + r) * N + ccol + fn * 16;
                out[idx] = acc1[fm][fn][r] * acc2[fm][fn][r];
            }
}

// ---------------------------------------------------------------------------
// Segmented parallel scan, 3-pass streaming with 4x batched loads (R18 state).
// ---------------------------------------------------------------------------
#define SSEG 32
#define SCHB 32
#define SSL (T_SEQ / SSEG)   // 64

__global__ __launch_bounds__(1024, 1)
void scan_kernel(u16* __restrict__ kq, u16* __restrict__ xyb)
{
    __shared__ float  lmax[SSEG][SCHB];
    __shared__ float2 lprod[SSEG][SCHB];
    const int blk = blockIdx.x;
    const int b   = blk >> 5;
    const int c0  = (blk & 31) * SCHB;
    const int ch  = threadIdx.x & (SCHB - 1);
    const int seg = threadIdx.x >> 5;
    const int c   = c0 + ch;
    const int t0  = seg * SSL;
    const size_t baseh = (size_t)b * T_SEQ * 2048 + 2 * c + (size_t)t0 * 2048;
    const size_t base1 = (size_t)b * T_SEQ * C_DIM + c + (size_t)t0 * C_DIM;

    // P1: segment max, loads batched 4-ahead
    float m2 = 0.f;
    {
        size_t idx = baseh;
        for (int g = 0; g < SSL / 4; ++g) {
            const u32 v0 = *(const u32*)&kq[idx];
            const u32 v1 = *(const u32*)&kq[idx + 2048];
            const u32 v2 = *(const u32*)&kq[idx + 4096];
            const u32 v3 = *(const u32*)&kq[idx + 6144];
            float re, im;
            re = h2f((u16)(v0 & 0xffffu)); im = h2f((u16)(v0 >> 16)); m2 = fmaxf(m2, re*re + im*im);
            re = h2f((u16)(v1 & 0xffffu)); im = h2f((u16)(v1 >> 16)); m2 = fmaxf(m2, re*re + im*im);
            re = h2f((u16)(v2 & 0xffffu)); im = h2f((u16)(v2 >> 16)); m2 = fmaxf(m2, re*re + im*im);
            re = h2f((u16)(v3 & 0xffffu)); im = h2f((u16)(v3 >> 16)); m2 = fmaxf(m2, re*re + im*im);
            idx += 4 * 2048;
        }
    }
    lmax[seg][ch] = sqrtf(m2);
    __syncthreads();
    #pragma unroll
    for (int s = 1; s < SSEG; s <<= 1) {
        const float v = lmax[seg][ch];
        const float u = (seg >= s) ? lmax[seg - s][ch] : 0.f;
        __syncthreads();
        lmax[seg][ch] = fmaxf(v, u);
        __syncthreads();
    }
    const float premax = (seg > 0) ? lmax[seg - 1][ch] : 0.f;

    // P2: seeded products + yb RMW, loads batched 4-ahead
    float pr = 1.f, pi = 0.f;
    float m = premax;
    {
        size_t idx = baseh, idx1 = base1;
        for (int g = 0; g < SSL / 4; ++g) {
            const u32 v0 = *(const u32*)&kq[idx];
            const u32 v1 = *(const u32*)&kq[idx + 2048];
            const u32 v2 = *(const u32*)&kq[idx + 4096];
            const u32 v3 = *(const u32*)&kq[idx + 6144];
            const u16 x0 = xyb[idx1];
            const u16 x1 = xyb[idx1 + C_DIM];
            const u16 x2 = xyb[idx1 + 2 * C_DIM];
            const u16 x3 = xyb[idx1 + 3 * C_DIM];
            u32 vv[4] = {v0, v1, v2, v3};
            u16 xx[4] = {x0, x1, x2, x3};
            #pragma unroll
            for (int q = 0; q < 4; ++q) {
                const float re = h2f((u16)(vv[q] & 0xffffu));
                const float im = h2f((u16)(vv[q] >> 16));
                m = fmaxf(m, sqrtf(re * re + im * im));
                const float inv = 1.f / m;
                const float r0 = re * inv, r1 = im * inv;
                const float nr = pr * r0 - pi * r1;
                const float ni = pr * r1 + pi * r0;
                pr = nr; pi = ni;
                xyb[idx1 + (size_t)q * C_DIM] = f2bf(h2f(xx[q]) * m);
            }
            idx += 4 * 2048; idx1 += 4 * C_DIM;
        }
    }
    lprod[seg][ch] = make_float2(pr, pi);
    __syncthreads();
    #pragma unroll
    for (int s = 1; s < SSEG; s <<= 1) {
        const float2 v = lprod[seg][ch];
        const float2 u = (seg >= s) ? lprod[seg - s][ch] : make_float2(1.f, 0.f);
        __syncthreads();
        lprod[seg][ch] = make_float2(u.x * v.x - u.y * v.y,
                                     u.x * v.y + u.y * v.x);
        __syncthreads();
    }
    float ppr = 1.f, ppi = 0.f;
    if (seg > 0) { const float2 pp = lprod[seg - 1][ch]; ppr = pp.x; ppi = pp.y; }

    // P3: recompute, scale by prefix, write kv (loads batched 4-ahead)
    pr = 1.f; pi = 0.f;
    m = premax;
    {
        size_t idx = baseh;
        for (int g = 0; g < SSL / 4; ++g) {
            const u32 v0 = *(const u32*)&kq[idx];
            const u32 v1 = *(const u32*)&kq[idx + 2048];
            const u32 v2 = *(const u32*)&kq[idx + 4096];
            const u32 v3 = *(const u32*)&kq[idx + 6144];
            u32 vv[4] = {v0, v1, v2, v3};
            u32 ww[4];
            #pragma unroll
            for (int q = 0; q < 4; ++q) {
                const float re = h2f((u16)(vv[q] & 0xffffu));
                const float im = h2f((u16)(vv[q] >> 16));
                m = fmaxf(m, sqrtf(re * re + im * im));
                const float inv = 1.f / m;
                const float r0 = re * inv, r1 = im * inv;
                const float nr = pr * r0 - pi * r1;
                const float ni = pr * r1 + pi * r0;
                pr = nr; pi = ni;
                const float fr = ppr * nr - ppi * ni;
                const float fi = ppr * ni + ppi * nr;
                ww[q] = ((u32)f2bf(fi) << 16) | (u32)f2bf(fr);
            }
            *(u32*)&kq[idx]        = ww[0];
            *(u32*)&kq[idx + 2048] = ww[1];
            *(u32*)&kq[idx + 4096] = ww[2];
            *(u32*)&kq[idx + 6144] = ww[3];
            idx += 4 * 2048;
        }
    }
}

// ---------------------------------------------------------------------------
// Prep kernels
// ---------------------------------------------------------------------------
__global__ void cvt_weights(const float* __restrict__ Wk, const float* __restrict__ Wa,
                            const float* __restrict__ Wo, u16* __restrict__ Wkh,
                            u16* __restrict__ Wab, u16* __restrict__ Wob)
{
    const int n1 = 2048 * 1024, n2 = 2 * 2048 * 1024, n3 = n2 + 1024 * 1024;
    const int i = (blockIdx.x * blockDim.x + threadIdx.x) * 4;
    if (i < n1) {
        const float4 v = *(const float4*)&Wk[i];
        ushort4 o; o.x = f2h(v.x); o.y = f2h(v.y); o.z = f2h(v.z); o.w = f2h(v.w);
        *(ushort4*)&Wkh[i] = o;
    } else if (i < n2) {
        const int j = i - n1;
        const float4 v = *(const float4*)&Wa[j];
        ushort4 o; o.x = f2bf(v.x); o.y = f2bf(v.y); o.z = f2bf(v.z); o.w = f2bf(v.w);
        *(ushort4*)&Wab[j] = o;
    } else if (i < n3) {
        const int j = i - n2;
        const float4 v = *(const float4*)&Wo[j];
        ushort4 o; o.x = f2bf(v.x); o.y = f2bf(v.y); o.z = f2bf(v.z); o.w = f2bf(v.w);
        *(ushort4*)&Wob[j] = o;
    }
}

__global__ void cvt_f16(const float* __restrict__ src, u16* __restrict__ dst, int n)
{
    const int i = (blockIdx.x * blockDim.x + threadIdx.x) * 4;
    if (i >= n) return;
    const float4 v = *(const float4*)&src[i];
    ushort4 o;
    o.x = f2h(v.x); o.y = f2h(v.y); o.z = f2h(v.z); o.w = f2h(v.w);
    *(ushort4*)&dst[i] = o;
}

// Wf/Wg [2,K,N] (tap,k,n) -> Wfgt [tap][F/G][n][k] bf16
__global__ __launch_bounds__(256)
void wtrans(const float* __restrict__ Wf, const float* __restrict__ Wg,
            u16* __restrict__ dst)
{
    __shared__ float tile[64][65];
    const int z = blockIdx.z;
    const float* src = ((z < 2) ? Wf : Wg) + (size_t)(z & 1) * C_DIM * C_DIM;
    u16* d = dst + (size_t)(z & 1) * (2 * C_DIM) * C_DIM
                 + ((z < 2) ? (size_t)0 : (size_t)C_DIM * C_DIM);
    const int k0 = blockIdx.x * 64;
    const int n0 = blockIdx.y * 64;
    const int tx = threadIdx.x & 63, ty = threadIdx.x >> 6;
    #pragma unroll
    for (int i = 0; i < 16; ++i) {
        const int r = ty + i * 4;
        tile[r][tx] = src[(size_t)(k0 + r) * C_DIM + n0 + tx];
    }
    __syncthreads();
    #pragma unroll
    for (int i = 0; i < 16; ++i) {
        const int r = ty + i * 4;
        d[(size_t)(n0 + r) * C_DIM + k0 + tx] = f2bf(tile[tx][r]);
    }
}

// ---------------------------------------------------------------------------
// ws layout (bytes):
//   0         : kq  u16 [16384,2048]  67.1MB  (kh fp16 -> kv bf16 in-place)
//   67108864  : yb  u16 [16384,1024]  33.6MB  (xh fp16 -> yb bf16 in-place)
//   100663296 : hb  u16 [16384,1024]  33.6MB
//   134217728 : Wkh(f16) 4.2 | Wab 4.2 | Wfgt 8.4 | Wob 2.1   (~153MB total)
// ---------------------------------------------------------------------------
extern "C" void kernel_launch(void* const* d_in, const int* in_sizes, int n_in,
                              void* d_out, int out_size, void* d_ws, size_t ws_size,
                              hipStream_t stream)
{
    const float* x  = (const float*)d_in[0];
    const float* Wk = (const float*)d_in[1];
    const float* Wa = (const float*)d_in[2];
    const float* Wf = (const float*)d_in[3];
    const float* Wg = (const float*)d_in[4];
    const float* Wo = (const float*)d_in[5];
    float* out = (float*)d_out;

    const int M = 8 * T_SEQ;
    u16* kq   = (u16*)d_ws;
    u16* yb   = (u16*)((char*)d_ws + 67108864ull);   // xh first, then yb
    u16* hb   = (u16*)((char*)d_ws + 100663296ull);
    u16* Wkh  = (u16*)((char*)d_ws + 134217728ull);
    u16* Wab  = Wkh + 2048 * 1024;
    u16* Wfgt = Wab + 2048 * 1024;
    u16* Wob  = Wfgt + 2ull * 2048 * 1024;

    cvt_weights<<<(5 * 1024 * 1024 / 4 + 255) / 256, 256, 0, stream>>>(
        Wk, Wa, Wo, Wkh, Wab, Wob);
    wtrans  <<<dim3(16, 16, 4), 256, 0, stream>>>(Wf, Wg, Wfgt);
    cvt_f16 <<<(M * 1024 / 4) / 256, 256, 0, stream>>>(x, yb, M * 1024);  // xh

    // 1) kq = fp16( x @ Wk^T )  (8-phase 256^2 fp16 MFMA)
    gemm8<<<dim3(2048 / 256, M / 256), 512, 0, stream>>>(
        yb, Wkh, kq, M, 2048, 1024);

    // 2) streaming scan (4x batched loads): kv bf16 in-place; yb in-place
    scan_kernel<<<256, 1024, 0, stream>>>(kq, yb);

    // 3) hb = bf16(tanh(conv(yb,Wf)) * sigmoid(conv(yb,Wg)))  (merged phases)
    conv8<<<dim3(1024 / 128, M / 256), 512, 0, stream>>>(yb, Wfgt, hb, M);

    // 4) out = (kv @ Wa^T) * (hb @ Wo^T)   (dual GEMM, product epilogue)
    dual_gemm<<<dim3(1024 / BN, M / BM), 256, 0, stream>>>(
        kq, Wab, 2048, hb, Wob, 1024, out, M, 1024);
}

// Round 21
// 441.208 us; speedup vs baseline: 1.1497x; 1.0157x over previous
//
#include <hip/hip_runtime.h>
#include <cmath>

#define T_SEQ 2048
#define C_DIM 1024

typedef unsigned short u16;
typedef unsigned int u32;
typedef short bf16x8 __attribute__((ext_vector_type(8)));
typedef _Float16 f16x8 __attribute__((ext_vector_type(8)));
typedef float f32x4 __attribute__((ext_vector_type(4)));
typedef unsigned short u16x8 __attribute__((ext_vector_type(8)));

#define AS1 __attribute__((address_space(1)))
#define AS3 __attribute__((address_space(3)))

__device__ __forceinline__ u16 f2bf(float f) {
    u32 u = __builtin_bit_cast(u32, f);
    u32 r = u + 0x7fffu + ((u >> 16) & 1u);
    return (u16)(r >> 16);
}
__device__ __forceinline__ u16 f2h(float f) {
    return __builtin_bit_cast(u16, (_Float16)f);
}
__device__ __forceinline__ float h2f(u16 h) {
    return (float)__builtin_bit_cast(_Float16, h);
}
__device__ __forceinline__ void gl_lds16(const void* g, void* l) {
    __builtin_amdgcn_global_load_lds((const AS1 u32*)g, (AS3 u32*)l, 16, 0, 0);
}

// XCD-aware bijective block swizzle (T1): all our grids have nwg % 8 == 0.
__device__ __forceinline__ int xcd_swz(int lin, int nwg) {
    return (lin & 7) * (nwg >> 3) + (lin >> 3);
}

#define SBAR() do { __builtin_amdgcn_sched_barrier(0); \
                    __builtin_amdgcn_s_barrier(); \
                    __builtin_amdgcn_sched_barrier(0); } while (0)
#define VMC(n) do { asm volatile("s_waitcnt vmcnt(" #n ")" ::: "memory"); \
                    __builtin_amdgcn_sched_barrier(0); } while (0)
#define LGKM0() do { asm volatile("s_waitcnt lgkmcnt(0)" ::: "memory"); \
                     __builtin_amdgcn_sched_barrier(0); } while (0)

// ---------------------------------------------------------------------------
// 8-phase 256x256 GEMM, m201-anatomy phases (validated R13-R20).
// DT:  0 = bf16 MFMA   1 = fp16 MFMA   (A and B same 16-bit dtype)
// EPI: 0 = Cout u16 = fp16(acc)
//      1 = Cout f32 = h2f(Cmul[idx]) * acc   (fused final multiply)
// ---------------------------------------------------------------------------
template<int DT, int EPI>
__global__ __launch_bounds__(512, 2)
void gemm8(const u16* __restrict__ Ap, const u16* __restrict__ Bp,
           void* __restrict__ Cout, const u16* __restrict__ Cmul,
           int M, int N, int K)
{
    __shared__ u16 lds[2 * 32768];
    const int tid  = threadIdx.x;
    const int lane = tid & 63;
    const int wid  = tid >> 6;        // 0..7
    const int wrow = wid >> 2;        // 0..1
    const int wcol = wid & 3;         // 0..3
    const int gx = gridDim.x;
    const int lin = xcd_swz(blockIdx.x + gx * blockIdx.y, gx * gridDim.y);
    const int m0 = (lin / gx) * 256;
    const int n0 = (lin % gx) * 256;
    const int NT = K / 64;

    f32x4 acc[8][4] = {};

    auto stageu = [&](int t, int u) {
        const int isB = u & 1, kh = u >> 1;
        u16* ubase = &lds[(t & 1) * 32768 + isB * 16384 + kh * 8192];
        const u16* src = isB ? Bp + (size_t)n0 * K : Ap + (size_t)m0 * K;
        const int k0 = t * 64 + kh * 32;
        #pragma unroll
        for (int j = 0; j < 2; ++j) {
            const int c = wid + 8 * j;
            const int p = c * 64 + lane;
            const int row = p >> 2;
            const int sp  = (p & 3) ^ ((row >> 1) & 3);
            gl_lds16(src + (size_t)row * K + k0 + sp * 8, ubase + c * 512);
        }
    };

    auto lda = [&](int buf, int kh, int mq, u16x8 (&a)[4]) {
        const u16* base = &lds[buf * 32768 + kh * 8192];
        #pragma unroll
        for (int f = 0; f < 4; ++f) {
            const int row = wrow * 128 + mq * 64 + f * 16 + (lane & 15);
            const int sp  = (lane >> 4) ^ ((row >> 1) & 3);
            a[f] = *(const u16x8*)&base[row * 32 + sp * 8];
        }
    };
    auto ldb = [&](int buf, int kh, u16x8 (&b)[4]) {
        const u16* base = &lds[buf * 32768 + 16384 + kh * 8192];
        #pragma unroll
        for (int f = 0; f < 4; ++f) {
            const int row = wcol * 64 + f * 16 + (lane & 15);
            const int sp  = (lane >> 4) ^ ((row >> 1) & 3);
            b[f] = *(const u16x8*)&base[row * 32 + sp * 8];
        }
    };
    auto mm = [&](const u16x8 (&a)[4], const u16x8 (&b)[4], int mq) {
        __builtin_amdgcn_s_setprio(1);
        #pragma unroll
        for (int fm = 0; fm < 4; ++fm)
            #pragma unroll
            for (int fn = 0; fn < 4; ++fn) {
                if constexpr (DT == 1)
                    acc[mq * 4 + fm][fn] = __builtin_amdgcn_mfma_f32_16x16x32_f16(
                        __builtin_bit_cast(f16x8, a[fm]), __builtin_bit_cast(f16x8, b[fn]),
                        acc[mq * 4 + fm][fn], 0, 0, 0);
                else
                    acc[mq * 4 + fm][fn] = __builtin_amdgcn_mfma_f32_16x16x32_bf16(
                        __builtin_bit_cast(bf16x8, a[fm]), __builtin_bit_cast(bf16x8, b[fn]),
                        acc[mq * 4 + fm][fn], 0, 0, 0);
            }
        __builtin_amdgcn_s_setprio(0);
    };

    stageu(0, 0); stageu(0, 1); stageu(0, 2); stageu(0, 3);
    VMC(0);
    SBAR();

    u16x8 a[4], b[4];
    for (int t = 0; t < NT; ++t) {
        const int buf = t & 1;
        const bool more = (t + 1 < NT);
        lda(buf, 0, 0, a); ldb(buf, 0, b);
        if (more) stageu(t + 1, 0);
        SBAR(); LGKM0();
        mm(a, b, 0);
        SBAR();
        lda(buf, 0, 1, a);
        if (more) { stageu(t + 1, 1); VMC(4); } else { VMC(0); }
        SBAR(); LGKM0();
        mm(a, b, 1);
        SBAR();
        lda(buf, 1, 0, a); ldb(buf, 1, b);
        if (more) stageu(t + 1, 2);
        SBAR(); LGKM0();
        mm(a, b, 0);
        SBAR();
        lda(buf, 1, 1, a);
        if (more) { stageu(t + 1, 3); VMC(4); }
        SBAR(); LGKM0();
        mm(a, b, 1);
        SBAR();
    }

    const int crow0 = m0 + wrow * 128 + ((lane >> 4) << 2);
    const int ccol  = n0 + wcol * 64 + (lane & 15);
    #pragma unroll
    for (int mi = 0; mi < 8; ++mi)
        #pragma unroll
        for (int fn = 0; fn < 4; ++fn)
            #pragma unroll
            for (int r = 0; r < 4; ++r) {
                const size_t idx = (size_t)(crow0 + mi * 16 + r) * N + ccol + fn * 16;
                if constexpr (EPI == 0)
                    ((u16*)Cout)[idx] = f2h(acc[mi][fn][r]);
                else
                    ((float*)Cout)[idx] = h2f(Cmul[idx]) * acc[mi][fn][r];
            }
}

// ---------------------------------------------------------------------------
// Merged-phase fused causal-conv + gate (best conv variant, R17/R18/R20):
//   H = bf16( tanh(conv(yb,Wf)) * sigmoid(conv(yb,Wg)) )
// ---------------------------------------------------------------------------
__global__ __launch_bounds__(512, 2)
void conv8(const u16* __restrict__ A, const u16* __restrict__ Wfgt,
           u16* __restrict__ H, int M)
{
    __shared__ u16 lds[2 * 32768];
    const int tid  = threadIdx.x;
    const int lane = tid & 63;
    const int wid  = tid >> 6;
    const int wrow = wid >> 1;        // 0..3
    const int wcol = wid & 1;         // 0..1
    const int gx = gridDim.x;         // 8
    const int lin = xcd_swz(blockIdx.x + gx * blockIdx.y, gx * gridDim.y);
    const int m0 = (lin / gx) * 256;
    const int n0 = (lin % gx) * 128;
    const int NT = 32;                // 2 taps x 16 K-tiles

    f32x4 accF[4][4] = {};
    f32x4 accG[4][4] = {};

    auto stageA = [&](int t, int kh) {
        u16* ubase = &lds[(t & 1) * 32768 + kh * 8192];
        const int tap = t >> 4;
        const int k0 = (t & 15) * 64 + kh * 32;
        const int sh = (tap == 0) ? 1 : 0;
        #pragma unroll
        for (int j = 0; j < 2; ++j) {
            const int c = wid + 8 * j;
            const int p = c * 64 + lane;
            const int row = p >> 2;
            const int sp  = (p & 3) ^ ((row >> 1) & 3);
            int grow = m0 + row - sh;
            if (grow < 0) grow = 0;
            gl_lds16(A + (size_t)grow * C_DIM + k0 + sp * 8, ubase + c * 512);
        }
    };
    auto stageB = [&](int t, int kh) {
        u16* ubase = &lds[(t & 1) * 32768 + 16384 + kh * 8192];
        const int tap = t >> 4;
        const int k0 = (t & 15) * 64 + kh * 32;
        const u16* BF = Wfgt + (size_t)tap * 2 * C_DIM * C_DIM;
        const u16* BG = BF + (size_t)C_DIM * C_DIM;
        #pragma unroll
        for (int j = 0; j < 2; ++j) {
            const int c = wid + 8 * j;
            const int isG = c >> 3;
            const int p = (c & 7) * 64 + lane;
            const int row = p >> 2;
            const int sp  = (p & 3) ^ ((row >> 1) & 3);
            const u16* src = (isG ? BG : BF) + (size_t)(n0 + row) * C_DIM + k0 + sp * 8;
            gl_lds16(src, ubase + isG * 4096 + (c & 7) * 512);
        }
    };

    auto lda4 = [&](int buf, int kh, bf16x8 (&a)[4]) {
        const u16* base = &lds[buf * 32768 + kh * 8192];
        #pragma unroll
        for (int f = 0; f < 4; ++f) {
            const int row = wrow * 64 + f * 16 + (lane & 15);
            const int sp  = (lane >> 4) ^ ((row >> 1) & 3);
            a[f] = *(const bf16x8*)&base[row * 32 + sp * 8];
        }
    };
    auto ldb4 = [&](int buf, int kh, int isG, bf16x8 (&b)[4]) {
        const u16* base = &lds[buf * 32768 + 16384 + kh * 8192 + isG * 4096];
        #pragma unroll
        for (int f = 0; f < 4; ++f) {
            const int row = wcol * 64 + f * 16 + (lane & 15);
            const int sp  = (lane >> 4) ^ ((row >> 1) & 3);
            b[f] = *(const bf16x8*)&base[row * 32 + sp * 8];
        }
    };
    auto mm4 = [&](const bf16x8 (&a)[4], const bf16x8 (&b)[4], f32x4 (&acc)[4][4]) {
        #pragma unroll
        for (int fm = 0; fm < 4; ++fm)
            #pragma unroll
            for (int fn = 0; fn < 4; ++fn)
                acc[fm][fn] = __builtin_amdgcn_mfma_f32_16x16x32_bf16(
                    a[fm], b[fn], acc[fm][fn], 0, 0, 0);
    };

    const bool zrow = (m0 % T_SEQ) == 0;        // block-uniform
    const bool zlane = (wrow == 0) && ((lane & 15) == 0);
    const bf16x8 zvec = {0,0,0,0,0,0,0,0};

    stageA(0, 0); stageB(0, 0); stageA(0, 1); stageB(0, 1);
    VMC(0);
    SBAR();

    bf16x8 a[4], bF[4], bG[4];
    for (int t = 0; t < NT; ++t) {
        const int buf = t & 1;
        const bool more = (t + 1 < NT);
        const bool z0 = zrow && (t < 16);       // tap-0 pass only
        // Q1: kh0 (F+G); stage A+B kh0(t+1)
        lda4(buf, 0, a); ldb4(buf, 0, 0, bF); ldb4(buf, 0, 1, bG);
        if (more) { stageA(t + 1, 0); stageB(t + 1, 0); VMC(4); } else { VMC(0); }
        SBAR(); LGKM0();
        if (z0 && zlane) a[0] = zvec;           // causal zero, after data landed
        __builtin_amdgcn_s_setprio(1);
        mm4(a, bF, accF); mm4(a, bG, accG);
        __builtin_amdgcn_s_setprio(0);
        SBAR();
        // Q2: kh1 (F+G); stage A+B kh1(t+1)
        lda4(buf, 1, a); ldb4(buf, 1, 0, bF); ldb4(buf, 1, 1, bG);
        if (more) { stageA(t + 1, 1); stageB(t + 1, 1); VMC(4); } else { VMC(0); }
        SBAR(); LGKM0();
        if (z0 && zlane) a[0] = zvec;
        __builtin_amdgcn_s_setprio(1);
        mm4(a, bF, accF); mm4(a, bG, accG);
        __builtin_amdgcn_s_setprio(0);
        SBAR();
    }

    const int crow0 = m0 + wrow * 64 + ((lane >> 4) << 2);
    const int ccol  = n0 + wcol * 64 + (lane & 15);
    #pragma unroll
    for (int fm = 0; fm < 4; ++fm)
        #pragma unroll
        for (int fn = 0; fn < 4; ++fn)
            #pragma unroll
            for (int r = 0; r < 4; ++r) {
                const float fv = accF[fm][fn][r];
                const float gv = accG[fm][fn][r];
                const float th = 1.0f - 2.0f / (expf(2.0f * fv) + 1.0f);
                const float sg = 1.0f / (1.0f + expf(-gv));
                H[(size_t)(crow0 + fm * 16 + r) * C_DIM + ccol + fn * 16] = f2bf(th * sg);
            }
}

// ---------------------------------------------------------------------------
// Segmented parallel scan, 3-pass streaming with 4x batched loads (R18 state).
// ---------------------------------------------------------------------------
#define SSEG 32
#define SCHB 32
#define SSL (T_SEQ / SSEG)   // 64

__global__ __launch_bounds__(1024, 1)
void scan_kernel(u16* __restrict__ kq, u16* __restrict__ xyb)
{
    __shared__ float  lmax[SSEG][SCHB];
    __shared__ float2 lprod[SSEG][SCHB];
    const int blk = blockIdx.x;
    const int b   = blk >> 5;
    const int c0  = (blk & 31) * SCHB;
    const int ch  = threadIdx.x & (SCHB - 1);
    const int seg = threadIdx.x >> 5;
    const int c   = c0 + ch;
    const int t0  = seg * SSL;
    const size_t baseh = (size_t)b * T_SEQ * 2048 + 2 * c + (size_t)t0 * 2048;
    const size_t base1 = (size_t)b * T_SEQ * C_DIM + c + (size_t)t0 * C_DIM;

    // P1: segment max, loads batched 4-ahead
    float m2 = 0.f;
    {
        size_t idx = baseh;
        for (int g = 0; g < SSL / 4; ++g) {
            const u32 v0 = *(const u32*)&kq[idx];
            const u32 v1 = *(const u32*)&kq[idx + 2048];
            const u32 v2 = *(const u32*)&kq[idx + 4096];
            const u32 v3 = *(const u32*)&kq[idx + 6144];
            float re, im;
            re = h2f((u16)(v0 & 0xffffu)); im = h2f((u16)(v0 >> 16)); m2 = fmaxf(m2, re*re + im*im);
            re = h2f((u16)(v1 & 0xffffu)); im = h2f((u16)(v1 >> 16)); m2 = fmaxf(m2, re*re + im*im);
            re = h2f((u16)(v2 & 0xffffu)); im = h2f((u16)(v2 >> 16)); m2 = fmaxf(m2, re*re + im*im);
            re = h2f((u16)(v3 & 0xffffu)); im = h2f((u16)(v3 >> 16)); m2 = fmaxf(m2, re*re + im*im);
            idx += 4 * 2048;
        }
    }
    lmax[seg][ch] = sqrtf(m2);
    __syncthreads();
    #pragma unroll
    for (int s = 1; s < SSEG; s <<= 1) {
        const float v = lmax[seg][ch];
        const float u = (seg >= s) ? lmax[seg - s][ch] : 0.f;
        __syncthreads();
        lmax[seg][ch] = fmaxf(v, u);
        __syncthreads();
    }
    const float premax = (seg > 0) ? lmax[seg - 1][ch] : 0.f;

    // P2: seeded products + yb RMW, loads batched 4-ahead
    float pr = 1.f, pi = 0.f;
    float m = premax;
    {
        size_t idx = baseh, idx1 = base1;
        for (int g = 0; g < SSL / 4; ++g) {
            const u32 v0 = *(const u32*)&kq[idx];
            const u32 v1 = *(const u32*)&kq[idx + 2048];
            const u32 v2 = *(const u32*)&kq[idx + 4096];
            const u32 v3 = *(const u32*)&kq[idx + 6144];
            const u16 x0 = xyb[idx1];
            const u16 x1 = xyb[idx1 + C_DIM];
            const u16 x2 = xyb[idx1 + 2 * C_DIM];
            const u16 x3 = xyb[idx1 + 3 * C_DIM];
            u32 vv[4] = {v0, v1, v2, v3};
            u16 xx[4] = {x0, x1, x2, x3};
            #pragma unroll
            for (int q = 0; q < 4; ++q) {
                const float re = h2f((u16)(vv[q] & 0xffffu));
                const float im = h2f((u16)(vv[q] >> 16));
                m = fmaxf(m, sqrtf(re * re + im * im));
                const float inv = 1.f / m;
                const float r0 = re * inv, r1 = im * inv;
                const float nr = pr * r0 - pi * r1;
                const float ni = pr * r1 + pi * r0;
                pr = nr; pi = ni;
                xyb[idx1 + (size_t)q * C_DIM] = f2bf(h2f(xx[q]) * m);
            }
            idx += 4 * 2048; idx1 += 4 * C_DIM;
        }
    }
    lprod[seg][ch] = make_float2(pr, pi);
    __syncthreads();
    #pragma unroll
    for (int s = 1; s < SSEG; s <<= 1) {
        const float2 v = lprod[seg][ch];
        const float2 u = (seg >= s) ? lprod[seg - s][ch] : make_float2(1.f, 0.f);
        __syncthreads();
        lprod[seg][ch] = make_float2(u.x * v.x - u.y * v.y,
                                     u.x * v.y + u.y * v.x);
        __syncthreads();
    }
    float ppr = 1.f, ppi = 0.f;
    if (seg > 0) { const float2 pp = lprod[seg - 1][ch]; ppr = pp.x; ppi = pp.y; }

    // P3: recompute, scale by prefix, write kv (loads batched 4-ahead)
    pr = 1.f; pi = 0.f;
    m = premax;
    {
        size_t idx = baseh;
        for (int g = 0; g < SSL / 4; ++g) {
            const u32 v0 = *(const u32*)&kq[idx];
            const u32 v1 = *(const u32*)&kq[idx + 2048];
            const u32 v2 = *(const u32*)&kq[idx + 4096];
            const u32 v3 = *(const u32*)&kq[idx + 6144];
            u32 vv[4] = {v0, v1, v2, v3};
            u32 ww[4];
            #pragma unroll
            for (int q = 0; q < 4; ++q) {
                const float re = h2f((u16)(vv[q] & 0xffffu));
                const float im = h2f((u16)(vv[q] >> 16));
                m = fmaxf(m, sqrtf(re * re + im * im));
                const float inv = 1.f / m;
                const float r0 = re * inv, r1 = im * inv;
                const float nr = pr * r0 - pi * r1;
                const float ni = pr * r1 + pi * r0;
                pr = nr; pi = ni;
                const float fr = ppr * nr - ppi * ni;
                const float fi = ppr * ni + ppi * nr;
                ww[q] = ((u32)f2bf(fi) << 16) | (u32)f2bf(fr);
            }
            *(u32*)&kq[idx]        = ww[0];
            *(u32*)&kq[idx + 2048] = ww[1];
            *(u32*)&kq[idx + 4096] = ww[2];
            *(u32*)&kq[idx + 6144] = ww[3];
            idx += 4 * 2048;
        }
    }
}

// ---------------------------------------------------------------------------
// Prep kernels
// ---------------------------------------------------------------------------
__global__ void cvt_weights(const float* __restrict__ Wk, const float* __restrict__ Wa,
                            const float* __restrict__ Wo, u16* __restrict__ Wkh,
                            u16* __restrict__ Wab, u16* __restrict__ Wob)
{
    const int n1 = 2048 * 1024, n2 = 2 * 2048 * 1024, n3 = n2 + 1024 * 1024;
    const int i = (blockIdx.x * blockDim.x + threadIdx.x) * 4;
    if (i < n1) {
        const float4 v = *(const float4*)&Wk[i];
        ushort4 o; o.x = f2h(v.x); o.y = f2h(v.y); o.z = f2h(v.z); o.w = f2h(v.w);
        *(ushort4*)&Wkh[i] = o;
    } else if (i < n2) {
        const int j = i - n1;
        const float4 v = *(const float4*)&Wa[j];
        ushort4 o; o.x = f2bf(v.x); o.y = f2bf(v.y); o.z = f2bf(v.z); o.w = f2bf(v.w);
        *(ushort4*)&Wab[j] = o;
    } else if (i < n3) {
        const int j = i - n2;
        const float4 v = *(const float4*)&Wo[j];
        ushort4 o; o.x = f2bf(v.x); o.y = f2bf(v.y); o.z = f2bf(v.z); o.w = f2bf(v.w);
        *(ushort4*)&Wob[j] = o;
    }
}

__global__ void cvt_f16(const float* __restrict__ src, u16* __restrict__ dst, int n)
{
    const int i = (blockIdx.x * blockDim.x + threadIdx.x) * 4;
    if (i >= n) return;
    const float4 v = *(const float4*)&src[i];
    ushort4 o;
    o.x = f2h(v.x); o.y = f2h(v.y); o.z = f2h(v.z); o.w = f2h(v.w);
    *(ushort4*)&dst[i] = o;
}

// Wf/Wg [2,K,N] (tap,k,n) -> Wfgt [tap][F/G][n][k] bf16
__global__ __launch_bounds__(256)
void wtrans(const float* __restrict__ Wf, const float* __restrict__ Wg,
            u16* __restrict__ dst)
{
    __shared__ float tile[64][65];
    const int z = blockIdx.z;
    const float* src = ((z < 2) ? Wf : Wg) + (size_t)(z & 1) * C_DIM * C_DIM;
    u16* d = dst + (size_t)(z & 1) * (2 * C_DIM) * C_DIM
                 + ((z < 2) ? (size_t)0 : (size_t)C_DIM * C_DIM);
    const int k0 = blockIdx.x * 64;
    const int n0 = blockIdx.y * 64;
    const int tx = threadIdx.x & 63, ty = threadIdx.x >> 6;
    #pragma unroll
    for (int i = 0; i < 16; ++i) {
        const int r = ty + i * 4;
        tile[r][tx] = src[(size_t)(k0 + r) * C_DIM + n0 + tx];
    }
    __syncthreads();
    #pragma unroll
    for (int i = 0; i < 16; ++i) {
        const int r = ty + i * 4;
        d[(size_t)(n0 + r) * C_DIM + k0 + tx] = f2bf(tile[tx][r]);
    }
}

// ---------------------------------------------------------------------------
// ws layout (bytes):
//   0         : kq   u16 [16384,2048] 67.1MB  (kh fp16 -> kv bf16 in-place)
//   67108864  : yb   u16 [16384,1024] 33.6MB  (xh fp16 -> yb bf16 in-place)
//   100663296 : hb   u16 [16384,1024] 33.6MB
//   134217728 : Wkh(f16) 4.2 | Wab 4.2 | Wfgt 8.4 | Wob 2.1  (18.9MB)
//   153092096 : acth u16 [16384,1024] 33.6MB   (~187MB total)
// ---------------------------------------------------------------------------
extern "C" void kernel_launch(void* const* d_in, const int* in_sizes, int n_in,
                              void* d_out, int out_size, void* d_ws, size_t ws_size,
                              hipStream_t stream)
{
    const float* x  = (const float*)d_in[0];
    const float* Wk = (const float*)d_in[1];
    const float* Wa = (const float*)d_in[2];
    const float* Wf = (const float*)d_in[3];
    const float* Wg = (const float*)d_in[4];
    const float* Wo = (const float*)d_in[5];
    float* out = (float*)d_out;

    const int M = 8 * T_SEQ;
    u16* kq   = (u16*)d_ws;
    u16* yb   = (u16*)((char*)d_ws + 67108864ull);   // xh first, then yb
    u16* hb   = (u16*)((char*)d_ws + 100663296ull);
    u16* Wkh  = (u16*)((char*)d_ws + 134217728ull);
    u16* Wab  = Wkh + 2048 * 1024;
    u16* Wfgt = Wab + 2048 * 1024;
    u16* Wob  = Wfgt + 2ull * 2048 * 1024;
    u16* acth = (u16*)((char*)d_ws + 153092096ull);

    cvt_weights<<<(5 * 1024 * 1024 / 4 + 255) / 256, 256, 0, stream>>>(
        Wk, Wa, Wo, Wkh, Wab, Wob);
    wtrans  <<<dim3(16, 16, 4), 256, 0, stream>>>(Wf, Wg, Wfgt);
    cvt_f16 <<<(M * 1024 / 4) / 256, 256, 0, stream>>>(x, yb, M * 1024);  // xh

    // 1) kq = fp16( x @ Wk^T )  (8-phase 256^2 fp16 MFMA)
    gemm8<1, 0><<<dim3(2048 / 256, M / 256), 512, 0, stream>>>(
        yb, Wkh, kq, nullptr, M, 2048, 1024);

    // 2) streaming scan (4x batched loads): kv bf16 in-place; yb in-place
    scan_kernel<<<256, 1024, 0, stream>>>(kq, yb);

    // 3) acth = fp16( kv @ Wa^T )  (8-phase bf16 MFMA)
    gemm8<0, 0><<<dim3(1024 / 256, M / 256), 512, 0, stream>>>(
        kq, Wab, acth, nullptr, M, 1024, 2048);

    // 4) hb = bf16(tanh(conv(yb,Wf)) * sigmoid(conv(yb,Wg)))  (merged phases)
    conv8<<<dim3(1024 / 128, M / 256), 512, 0, stream>>>(yb, Wfgt, hb, M);

    // 5) out = acth * (hb @ Wo^T)  (8-phase bf16 MFMA, fused multiply epilogue)
    gemm8<0, 1><<<dim3(1024 / 256, M / 256), 512, 0, stream>>>(
        hb, Wob, out, acth, M, 1024, 1024);
}